// Round 5
// baseline (440.670 us; speedup 1.0000x reference)
//
#include <hip/hip_runtime.h>

typedef short s16x8 __attribute__((ext_vector_type(8)));
typedef short s16x4 __attribute__((ext_vector_type(4)));
typedef float f32x4 __attribute__((ext_vector_type(4)));

#define N_ROWS 10000
#define MP 10048      // padded adj dim (157*64)
#define KT_ADJ 157

__device__ inline short f2bf(float f) {
    unsigned u = __builtin_bit_cast(unsigned, f);
    unsigned r = (u + 0x7fffu + ((u >> 16) & 1u)) >> 16;
    return (short)r;
}

// swizzled index within one 64-col tile (units: bf16 elements)
__device__ inline int swz64(int r, int c) {
    return (r * 64 + c) ^ ((r & 7) << 3);
}

// async global->LDS, 16 bytes per lane (lane offset implicit on LDS side)
__device__ inline void gload16(const void* g, void* l) {
    __builtin_amdgcn_global_load_lds(
        (const __attribute__((address_space(1))) unsigned int*)g,
        (__attribute__((address_space(3))) unsigned int*)l, 16, 0, 0);
}

// ---------------------------------------------------------------------------
// MFMA GEMM, m97-style: double-buffered LDS, global_load_lds staging,
// one barrier per K-tile.
//  AIMG=1: A from pre-swizzled bf16 image: Aimg + (bx*aTiles + t)*BM*64.
//  AIMG=0: A = f32 row-major (Ap,ldA,Mval,Kval), reg-staged+converted,
//          depth-2 prefetch; CONVB=1 also stores converted tile to AoutImg.
//  B: always pre-swizzled image, tile stride BN*64.
//  EPI 0: store C^T as B-image for a consumer with N=ldC (tile stride ldC*64)
//  EPI 3: store f32 partial -> ((float*)Cp + blockIdx.y*MP*BN)[gm*BN + gc]
// ---------------------------------------------------------------------------
template<int BM, int BN, int WM, int WN, int AIMG, int EPI, int CONVB>
__global__ __launch_bounds__(512)
void gemm_gl(const void* __restrict__ Ap, int ldA, int Mval, int Kval,
             int aTiles,
             const short* __restrict__ Bimg,
             int Ktiles, int ktPerSplit,
             void* __restrict__ Cp, int ldC, int Cval,
             const float* __restrict__ bias,
             short* __restrict__ AoutImg)
{
    constexpr int WTM = BM / WM, WTN = BN / WN;
    constexpr int M_rep = WTM / 16, N_rep = WTN / 16;
    constexpr int ACH = BM / 8;   // 1KB chunks per A tile
    constexpr int BCH = BN / 8;

    __shared__ alignas(16) short Alds[2][BM * 64];
    __shared__ alignas(16) short Blds[2][BN * 64];

    const int tid  = threadIdx.x;
    const int lane = tid & 63;
    const int w    = tid >> 6;
    const int wr   = w / WN, wc = w % WN;
    const int m0   = blockIdx.x * BM;

    // f32 A prefetch registers, two sets (AIMG=0 only)
    float4 a0[2], a1[2];
    const int arow = tid >> 3, acol = (tid & 7) * 8;

    auto loadA = [&](int s, int kt) {
        if (arow < BM) {
            int gm = m0 + arow, gk = kt * 64 + acol;
            float4 z = {0.f, 0.f, 0.f, 0.f};
            a0[s] = z; a1[s] = z;
            if (gm < Mval && gk < Kval) {
                const float* p = (const float*)Ap + (long)gm * ldA + gk;
                a0[s] = *(const float4*)p;
                a1[s] = *(const float4*)(p + 4);
            }
        }
    };
    auto writeA = [&](int buf, int s, int kt) {
        if (arow < BM) {
            s16x8 b;
            b[0]=f2bf(a0[s].x); b[1]=f2bf(a0[s].y); b[2]=f2bf(a0[s].z); b[3]=f2bf(a0[s].w);
            b[4]=f2bf(a1[s].x); b[5]=f2bf(a1[s].y); b[6]=f2bf(a1[s].z); b[7]=f2bf(a1[s].w);
            *(s16x8*)(&Alds[buf][swz64(arow, acol)]) = b;
            if constexpr (CONVB) {
                *(s16x8*)(AoutImg + ((size_t)blockIdx.x * aTiles + kt) * (BM * 64)
                          + swz64(arow, acol)) = b;
            }
        }
    };
    auto stageA = [&](int buf, int kt) {   // AIMG path
        const short* src = (const short*)Ap + ((size_t)blockIdx.x * aTiles + kt) * (BM * 64);
        #pragma unroll
        for (int j = 0; j < ACH / 8; ++j) {
            int ch = w + j * 8;
            gload16(src + ch * 512 + lane * 8, &Alds[buf][ch * 512]);
        }
        if constexpr (ACH % 8) {   // BM=32: 4 chunks, waves 0-3 only
            if (w < (ACH % 8))
                gload16(src + (ACH / 8) * 8 * 512 + w * 512 + lane * 8,
                        &Alds[buf][((ACH / 8) * 8 + w) * 512]);
        }
    };
    auto stageB = [&](int buf, int kt) {
        const short* src = Bimg + (size_t)kt * (BN * 64);
        #pragma unroll
        for (int j = 0; j < BCH / 8; ++j) {
            int ch = w + j * 8;
            gload16(src + ch * 512 + lane * 8, &Blds[buf][ch * 512]);
        }
        if constexpr (BCH % 8) {
            if (w < (BCH % 8))
                gload16(src + (BCH / 8) * 8 * 512 + w * 512 + lane * 8,
                        &Blds[buf][((BCH / 8) * 8 + w) * 512]);
        }
    };

    f32x4 acc[M_rep][N_rep];
    const f32x4 zero4 = {0.f, 0.f, 0.f, 0.f};
    #pragma unroll
    for (int mi = 0; mi < M_rep; ++mi)
        #pragma unroll
        for (int nj = 0; nj < N_rep; ++nj) acc[mi][nj] = zero4;

    auto compute = [&](int buf) {
        #pragma unroll
        for (int kk = 0; kk < 2; ++kk) {
            const int krd = kk * 32 + (lane >> 4) * 8;
            s16x8 af[M_rep], bf[N_rep];
            #pragma unroll
            for (int mi = 0; mi < M_rep; ++mi) {
                int row = wr * WTM + mi * 16 + (lane & 15);
                af[mi] = *(const s16x8*)(&Alds[buf][swz64(row, krd)]);
            }
            #pragma unroll
            for (int nj = 0; nj < N_rep; ++nj) {
                int row = wc * WTN + nj * 16 + (lane & 15);
                bf[nj] = *(const s16x8*)(&Blds[buf][swz64(row, krd)]);
            }
            #pragma unroll
            for (int mi = 0; mi < M_rep; ++mi)
                #pragma unroll
                for (int nj = 0; nj < N_rep; ++nj)
                    acc[mi][nj] = __builtin_amdgcn_mfma_f32_16x16x32_bf16(
                        af[mi], bf[nj], acc[mi][nj], 0, 0, 0);
        }
    };

    const int kt0 = blockIdx.y * ktPerSplit;
    int ktEnd = kt0 + ktPerSplit;
    if (ktEnd > Ktiles) ktEnd = Ktiles;

    // ---- prologue: stage tile kt0 into buf 0 ----
    if constexpr (AIMG) {
        stageA(0, kt0);
    } else {
        loadA(0, kt0);
    }
    stageB(0, kt0);
    if constexpr (!AIMG) {
        writeA(0, 0, kt0);
        if (kt0 + 1 < ktEnd) loadA(1, kt0 + 1);
    }
    __syncthreads();   // drains vmcnt (gload_lds arrived) + lgkm (A writes)

    // ---- main loop: one barrier per tile ----
    for (int t = kt0; t < ktEnd; ++t) {
        const int cur = (t - kt0) & 1;
        if (t + 1 < ktEnd) {
            stageB(cur ^ 1, t + 1);
            if constexpr (AIMG) {
                stageA(cur ^ 1, t + 1);
            } else {
                writeA(cur ^ 1, cur ^ 1, t + 1);   // set parity(t+1) = cur^1
            }
        }
        if constexpr (!AIMG) {
            if (t + 2 < ktEnd) loadA(cur, t + 2);  // set parity(t+2) = cur
        }
        compute(cur);
        __syncthreads();
    }

    // ---- epilogue ----
    const int mbase = m0 + wr * WTM;
    if constexpr (EPI == 0) {
        // store C^T as B-image: consumer N = ldC rows, tile stride ldC*64
        short* img = (short*)Cp;
        #pragma unroll
        for (int mi = 0; mi < M_rep; ++mi) {
            int gm = mbase + mi * 16 + (lane >> 4) * 4;
            if (gm >= Cval) continue;
            #pragma unroll
            for (int nj = 0; nj < N_rep; ++nj) {
                int gc = wc * WTN + nj * 16 + (lane & 15);
                s16x4 p;
                #pragma unroll
                for (int r = 0; r < 4; ++r) p[r] = f2bf(acc[mi][nj][r]);
                *(s16x4*)(img + (size_t)(gm >> 6) * (ldC * 64) + swz64(gc, gm & 63)) = p;
            }
        }
    } else {
        // EPI == 3: f32 partial, one buffer per K-split
        float* Cpart = (float*)Cp + (size_t)blockIdx.y * MP * BN;
        #pragma unroll
        for (int nj = 0; nj < N_rep; ++nj) {
            int gc = wc * WTN + nj * 16 + (lane & 15);
            #pragma unroll
            for (int mi = 0; mi < M_rep; ++mi) {
                int gm = mbase + mi * 16 + (lane >> 4) * 4;
                #pragma unroll
                for (int r = 0; r < 4; ++r)
                    Cpart[(long)(gm + r) * BN + gc] = acc[mi][nj][r];
            }
        }
    }
}

// H = relu(sum_s P[s] + b1) -> H image ([MP/64 x 4] tiles of 64x64, swizzled)
__global__ __launch_bounds__(256)
void reduce_relu(const float* __restrict__ P, const float* __restrict__ b1,
                 short* __restrict__ Himg, int KS)
{
    int idx4 = blockIdx.x * 256 + threadIdx.x;
    int row  = idx4 >> 6;
    int col  = (idx4 & 63) * 4;
    s16x4 o;
    if (row < N_ROWS) {
        f32x4 s = {0.f, 0.f, 0.f, 0.f};
        if (KS == 8) {
            #pragma unroll
            for (int k = 0; k < 8; ++k)
                s += *(const f32x4*)(P + (size_t)k * MP * 256 + (size_t)row * 256 + col);
        } else {
            for (int k = 0; k < KS; ++k)
                s += *(const f32x4*)(P + (size_t)k * MP * 256 + (size_t)row * 256 + col);
        }
        #pragma unroll
        for (int j = 0; j < 4; ++j)
            o[j] = f2bf(fmaxf(s[j] + b1[col + j], 0.f));
    } else {
        o[0] = o[1] = o[2] = o[3] = 0;
    }
    *(s16x4*)(Himg + ((size_t)(row >> 6) * 4 + (col >> 6)) * 4096
              + swz64(row & 63, col & 63)) = o;
}

// out = log_softmax(sum_s P[s] + b2) over 40 cols; P rows are 64 wide
__global__ __launch_bounds__(256)
void reduce_softmax(const float* __restrict__ P, const float* __restrict__ b2,
                    float* __restrict__ out, int KS)
{
    int lane = threadIdx.x & 63;
    int row  = blockIdx.x * 4 + (threadIdx.x >> 6);
    if (row >= N_ROWS) return;
    float v = 0.f;
    if (KS == 8) {
        #pragma unroll
        for (int k = 0; k < 8; ++k)
            v += P[(size_t)k * MP * 64 + (size_t)row * 64 + lane];
    } else {
        for (int k = 0; k < KS; ++k)
            v += P[(size_t)k * MP * 64 + (size_t)row * 64 + lane];
    }
    float vv = (lane < 40) ? v + b2[lane] : -__builtin_inff();
    float mx = vv;
    #pragma unroll
    for (int off = 1; off < 64; off <<= 1)
        mx = fmaxf(mx, __shfl_xor(mx, off));
    float e = (lane < 40) ? __expf(vv - mx) : 0.f;
    float s = e;
    #pragma unroll
    for (int off = 1; off < 64; off <<= 1)
        s += __shfl_xor(s, off);
    float lse = mx + __logf(s);
    if (lane < 40) out[(size_t)row * 40 + lane] = vv - lse;
}

// weight prep: W1 [512][256] -> W1 image (8 tiles x 256x64);
//              W2 [256][40]  -> W2 image (4 tiles x 64x64, cols padded to 64)
__global__ __launch_bounds__(256)
void prep_weights(const float* __restrict__ W1, const float* __restrict__ W2,
                  short* __restrict__ W1img, short* __restrict__ W2img)
{
    int bid = blockIdx.x, c = threadIdx.x;
    if (bid < 512) {
        int k = bid;
        W1img[(size_t)(k >> 6) * 16384 + swz64(c, k & 63)] = f2bf(W1[k * 256 + c]);
    } else {
        int k = bid - 512;
        if (c < 64) {
            float v = (c < 40) ? W2[k * 40 + c] : 0.f;
            W2img[(size_t)(k >> 6) * 4096 + swz64(c, k & 63)] = f2bf(v);
        }
    }
}

extern "C" void kernel_launch(void* const* d_in, const int* in_sizes, int n_in,
                              void* d_out, int out_size, void* d_ws, size_t ws_size,
                              hipStream_t stream)
{
    const float* feature = (const float*)d_in[0];  // [10000,512]
    const float* adj     = (const float*)d_in[1];  // [10000,10000]
    const float* W1      = (const float*)d_in[2];  // [512,256]
    const float* b1      = (const float*)d_in[3];  // [256]
    const float* W2      = (const float*)d_in[4];  // [256,40]
    const float* b2      = (const float*)d_in[5];  // [40]
    float* out = (float*)d_out;                    // [10000,40]

    char* w = (char*)d_ws;
    short* XWimg = (short*)w;  w += (size_t)KT_ADJ * 16384 * 2;      // 5.1 MB
    short* Himg  = (short*)w;  w += (size_t)MP * 256 * 2;            // 5.1 MB
    short* HWimg = (short*)w;  w += (size_t)KT_ADJ * 4096 * 2;       // 1.3 MB
    short* W1img = (short*)w;  w += (size_t)8 * 16384 * 2;           // 256 KB
    short* W2img = (short*)w;  w += (size_t)4 * 4096 * 2;            // 32 KB
    char*  base_end = w;
    short* adjB  = (short*)w;  w += (size_t)KT_ADJ * KT_ADJ * 4096 * 2; // 202 MB
    float* Pfull = (float*)w;
    size_t offFull = (size_t)((char*)Pfull - (char*)d_ws);
    size_t offB    = (size_t)(base_end - (char*)d_ws);
    const size_t pbytes = (size_t)MP * 256 * 4;

    prep_weights<<<768, 256, 0, stream>>>(W1, W2, W1img, W2img);

    // G1: XW = feature @ W1 -> XW image (consumer N=256)
    gemm_gl<32, 256, 2, 4, 0, 0, 0><<<314, 512, 0, stream>>>(
        feature, 512, N_ROWS, 512, 0, W1img, 8, 8, XWimg, 256, MP, nullptr, nullptr);

    if (ws_size >= offFull + 8 * pbytes) {
        // full path: KS=8 split, fused adj->bf16 image emission in G2
        const int KS = 8, KTS = (KT_ADJ + KS - 1) / KS;
        float* P = Pfull;
        // G2: partials = adj @ XW; emits adjB image
        gemm_gl<64, 256, 2, 4, 0, 3, 1><<<dim3(KT_ADJ, KS), 512, 0, stream>>>(
            adj, N_ROWS, N_ROWS, N_ROWS, KT_ADJ, XWimg, KT_ADJ, KTS, P, 256, MP, nullptr, adjB);
        // R1: H = relu(sum + b1) -> H image
        reduce_relu<<<MP * 256 / 4 / 256, 256, 0, stream>>>(P, b1, Himg, KS);
        // G3: HW = H @ W2 -> HW image (consumer N=64); A = H image (4 tiles/rowblock)
        gemm_gl<64, 64, 4, 2, 1, 0, 0><<<KT_ADJ, 512, 0, stream>>>(
            Himg, 0, 0, 0, 4, W2img, 4, 4, HWimg, 64, MP, nullptr, nullptr);
        // G4: partials = adjB @ HW (fully image-staged)
        gemm_gl<64, 64, 4, 2, 1, 3, 0><<<dim3(KT_ADJ, KS), 512, 0, stream>>>(
            adjB, 0, 0, 0, KT_ADJ, HWimg, KT_ADJ, KTS, P, 64, MP, nullptr, nullptr);
        // R2: out = log_softmax(sum + b2)
        reduce_softmax<<<2500, 256, 0, stream>>>(P, b2, out, KS);
    } else {
        // fallback: no adjB image; G4 re-reads adj as f32 (reg-staged A)
        float* P = (float*)base_end;
        int KS = 1;
        if (ws_size >= offB + 8 * pbytes) KS = 8;
        else if (ws_size >= offB + 4 * pbytes) KS = 4;
        else if (ws_size >= offB + 2 * pbytes) KS = 2;
        const int KTS = (KT_ADJ + KS - 1) / KS;
        gemm_gl<64, 256, 2, 4, 0, 3, 0><<<dim3(KT_ADJ, KS), 512, 0, stream>>>(
            adj, N_ROWS, N_ROWS, N_ROWS, 0, XWimg, KT_ADJ, KTS, P, 256, MP, nullptr, nullptr);
        reduce_relu<<<MP * 256 / 4 / 256, 256, 0, stream>>>(P, b1, Himg, KS);
        gemm_gl<64, 64, 4, 2, 1, 0, 0><<<KT_ADJ, 512, 0, stream>>>(
            Himg, 0, 0, 0, 4, W2img, 4, 4, HWimg, 64, MP, nullptr, nullptr);
        gemm_gl<64, 64, 4, 2, 0, 3, 0><<<dim3(KT_ADJ, KS), 512, 0, stream>>>(
            adj, N_ROWS, N_ROWS, N_ROWS, 0, HWimg, KT_ADJ, KTS, P, 64, MP, nullptr, nullptr);
        reduce_softmax<<<2500, 256, 0, stream>>>(P, b2, out, KS);
    }
}

// Round 6
// 259.784 us; speedup vs baseline: 1.6963x; 1.6963x over previous
//
#include <hip/hip_runtime.h>

typedef short s16x8 __attribute__((ext_vector_type(8)));
typedef short s16x4 __attribute__((ext_vector_type(4)));
typedef float f32x4 __attribute__((ext_vector_type(4)));

#define N_ROWS 10000
#define MP 10048   // padded M/K for adj dim (157*64)

__device__ inline short f2bf(float f) {
    unsigned u = __builtin_bit_cast(unsigned, f);
    unsigned r = (u + 0x7fffu + ((u >> 16) & 1u)) >> 16;
    return (short)r;
}
__device__ inline float bf2f(short b) {
    return __builtin_bit_cast(float, ((unsigned)(unsigned short)b) << 16);
}

// swizzled LDS index (units: bf16 elements, rows of 64)
__device__ inline int swz(int row, int col) {
    return (row * 64 + col) ^ ((row & 7) << 3);
}

// ---------------------------------------------------------------------------
// Unified MFMA GEMM with depth-1 register prefetch (round-3 structure).
//  C[M x BN] = A[M x K] * B[K x BN]
//  A: row-major, f32 (AF32=1, converted on the fly) or bf16 bits (AF32=0)
//  B: given TRANSPOSED as Bt[BN][ldBt] bf16 bits (row n = column n of B)
//  K-split: blockIdx.y picks tile range [y*ktPerSplit, min(+ktPerSplit,Ktiles))
//  EPI 0: store C^T bf16 -> Cp[gc*ldC + gm]
//  EPI 1: store relu(C + bias) bf16 row-major -> Cp[gm*ldC + gc]
//  EPI 2: logits = C + bias; row log_softmax; store f32 -> Cp[gm*ldC+gc], gc<40
//  EPI 3: store bf16 partial -> ((short*)Cp + y*MP*BN)[gm*BN + gc]
// ---------------------------------------------------------------------------
template<int BM, int BN, int WM, int WN, int AF32, int EPI>
__global__ __launch_bounds__(512)
void gemm_k(const void* __restrict__ Ap, int ldA, int Mval, int Kval,
            const short* __restrict__ Bt, int ldBt, int Ktiles,
            void* __restrict__ Cp, int ldC, int Cval,
            const float* __restrict__ bias, int ktPerSplit)
{
    constexpr int WTM = BM / WM, WTN = BN / WN;
    constexpr int M_rep = WTM / 16, N_rep = WTN / 16;
    constexpr int AREP = BM / 64, BREP = BN / 64;

    __shared__ alignas(16) short Alds[BM * 64];
    __shared__ alignas(16) short Blds[BN * 64];

    const int tid  = threadIdx.x;
    const int lane = tid & 63;
    const int w    = tid >> 6;
    const int wr   = w / WN, wc = w % WN;
    const int m0   = blockIdx.x * BM;

    // prefetch registers (statically indexed via unrolled loops)
    float4 va0[AREP], va1[AREP];
    s16x8  vab[AREP];
    s16x8  vb[BREP];

    auto load_regs = [&](int kt) {
        const int k0 = kt * 64;
        #pragma unroll
        for (int rep = 0; rep < AREP; ++rep) {
            int e   = tid + rep * 512;
            int row = e >> 3, cc = (e & 7) * 8;
            int gm  = m0 + row, gk = k0 + cc;
            if constexpr (AF32) {
                float4 z = {0.f, 0.f, 0.f, 0.f};
                va0[rep] = z; va1[rep] = z;
                if (gm < Mval && gk < Kval) {
                    const float* p = (const float*)Ap + (long)gm * ldA + gk;
                    va0[rep] = *(const float4*)p;
                    va1[rep] = *(const float4*)(p + 4);
                }
            } else {
                if (gm < Mval && gk < Kval) {
                    vab[rep] = *(const s16x8*)((const short*)Ap + (long)gm * ldA + gk);
                } else {
                    s16x8 z;
                    #pragma unroll
                    for (int j = 0; j < 8; ++j) z[j] = 0;
                    vab[rep] = z;
                }
            }
        }
        #pragma unroll
        for (int rep = 0; rep < BREP; ++rep) {
            int e   = tid + rep * 512;
            int row = e >> 3, cc = (e & 7) * 8;
            vb[rep] = *(const s16x8*)(Bt + (long)row * ldBt + k0 + cc);
        }
    };

    auto write_lds = [&]() {
        #pragma unroll
        for (int rep = 0; rep < AREP; ++rep) {
            int e   = tid + rep * 512;
            int row = e >> 3, cc = (e & 7) * 8;
            s16x8 b;
            if constexpr (AF32) {
                b[0]=f2bf(va0[rep].x); b[1]=f2bf(va0[rep].y);
                b[2]=f2bf(va0[rep].z); b[3]=f2bf(va0[rep].w);
                b[4]=f2bf(va1[rep].x); b[5]=f2bf(va1[rep].y);
                b[6]=f2bf(va1[rep].z); b[7]=f2bf(va1[rep].w);
            } else {
                b = vab[rep];
            }
            *(s16x8*)(&Alds[swz(row, cc)]) = b;
        }
        #pragma unroll
        for (int rep = 0; rep < BREP; ++rep) {
            int e   = tid + rep * 512;
            int row = e >> 3, cc = (e & 7) * 8;
            *(s16x8*)(&Blds[swz(row, cc)]) = vb[rep];
        }
    };

    f32x4 acc[M_rep][N_rep];
    const f32x4 zero4 = {0.f, 0.f, 0.f, 0.f};
    #pragma unroll
    for (int mi = 0; mi < M_rep; ++mi)
        #pragma unroll
        for (int nj = 0; nj < N_rep; ++nj) acc[mi][nj] = zero4;

    const int kt0 = blockIdx.y * ktPerSplit;
    int ktEnd = kt0 + ktPerSplit;
    if (ktEnd > Ktiles) ktEnd = Ktiles;

    // prologue: stage first tile
    load_regs(kt0);
    write_lds();

    for (int kt = kt0; kt < ktEnd; ++kt) {
        __syncthreads();                       // staged tile visible
        if (kt + 1 < ktEnd) load_regs(kt + 1); // issue next loads (hide under compute)
        // ---- compute tile kt ----
        #pragma unroll
        for (int kk = 0; kk < 2; ++kk) {
            const int krd = kk * 32 + (lane >> 4) * 8;
            s16x8 af[M_rep], bf[N_rep];
            #pragma unroll
            for (int mi = 0; mi < M_rep; ++mi) {
                int row = wr * WTM + mi * 16 + (lane & 15);
                af[mi] = *(const s16x8*)(&Alds[swz(row, krd)]);
            }
            #pragma unroll
            for (int nj = 0; nj < N_rep; ++nj) {
                int row = wc * WTN + nj * 16 + (lane & 15);
                bf[nj] = *(const s16x8*)(&Blds[swz(row, krd)]);
            }
            #pragma unroll
            for (int mi = 0; mi < M_rep; ++mi)
                #pragma unroll
                for (int nj = 0; nj < N_rep; ++nj)
                    acc[mi][nj] = __builtin_amdgcn_mfma_f32_16x16x32_bf16(
                        af[mi], bf[nj], acc[mi][nj], 0, 0, 0);
        }
        __syncthreads();                       // all reads done before overwrite
        if (kt + 1 < ktEnd) write_lds();       // vmcnt wait happens here
    }

    // ---- epilogue ----
    const int mbase = m0 + wr * WTM;
    if constexpr (EPI == 0) {
        short* CT = (short*)Cp;
        #pragma unroll
        for (int mi = 0; mi < M_rep; ++mi) {
            int gm = mbase + mi * 16 + (lane >> 4) * 4;
            if (gm >= Cval) continue;
            #pragma unroll
            for (int nj = 0; nj < N_rep; ++nj) {
                int gc = wc * WTN + nj * 16 + (lane & 15);
                s16x4 p;
                #pragma unroll
                for (int r = 0; r < 4; ++r) p[r] = f2bf(acc[mi][nj][r]);
                *(s16x4*)(CT + (long)gc * ldC + gm) = p;
            }
        }
    } else if constexpr (EPI == 1) {
        short* C = (short*)Cp;
        #pragma unroll
        for (int nj = 0; nj < N_rep; ++nj) {
            int gc = wc * WTN + nj * 16 + (lane & 15);
            float b = bias[gc];
            #pragma unroll
            for (int mi = 0; mi < M_rep; ++mi) {
                int gm = mbase + mi * 16 + (lane >> 4) * 4;
                #pragma unroll
                for (int r = 0; r < 4; ++r) {
                    float v = acc[mi][nj][r] + b;
                    v = fmaxf(v, 0.f);
                    C[(long)(gm + r) * ldC + gc] = f2bf(v);
                }
            }
        }
    } else if constexpr (EPI == 2) {
        // requires WN==1, M_rep==1, N_rep==4 (BN=64 covers all cols)
        float* out = (float*)Cp;
        const int gmb = mbase + (lane >> 4) * 4;
        #pragma unroll
        for (int r = 0; r < 4; ++r) {
            float v[4];
            float mx = -__builtin_inff();
            #pragma unroll
            for (int nj = 0; nj < 4; ++nj) {
                int gc = nj * 16 + (lane & 15);
                float vv = -__builtin_inff();
                if (gc < 40) vv = acc[0][nj][r] + bias[gc];
                v[nj] = vv;
                mx = fmaxf(mx, vv);
            }
            #pragma unroll
            for (int off = 1; off < 16; off <<= 1)
                mx = fmaxf(mx, __shfl_xor(mx, off));
            float s = 0.f;
            #pragma unroll
            for (int nj = 0; nj < 4; ++nj)
                s += (v[nj] == -__builtin_inff()) ? 0.f : __expf(v[nj] - mx);
            #pragma unroll
            for (int off = 1; off < 16; off <<= 1)
                s += __shfl_xor(s, off);
            float lse = mx + __logf(s);
            int gm = gmb + r;
            if (gm < Cval) {
                #pragma unroll
                for (int nj = 0; nj < 4; ++nj) {
                    int gc = nj * 16 + (lane & 15);
                    if (gc < 40) out[(long)gm * ldC + gc] = v[nj] - lse;
                }
            }
        }
    } else {
        // EPI == 3: bf16 partial store, one buffer per K-split
        short* Cpart = (short*)Cp + (size_t)blockIdx.y * MP * BN;
        #pragma unroll
        for (int nj = 0; nj < N_rep; ++nj) {
            int gc = wc * WTN + nj * 16 + (lane & 15);
            #pragma unroll
            for (int mi = 0; mi < M_rep; ++mi) {
                int gm = mbase + mi * 16 + (lane >> 4) * 4;
                #pragma unroll
                for (int r = 0; r < 4; ++r)
                    Cpart[(long)(gm + r) * BN + gc] = f2bf(acc[mi][nj][r]);
            }
        }
    }
}

// H = relu(sum_s P[s] + b1), bf16 [MP][256]; pad rows -> 0. P: bf16 partials.
__global__ __launch_bounds__(256)
void reduce_relu(const short* __restrict__ P, const float* __restrict__ b1,
                 short* __restrict__ H, int KS)
{
    int idx4 = blockIdx.x * 256 + threadIdx.x;   // one 4-col chunk
    int row  = idx4 >> 6;
    int col  = (idx4 & 63) * 4;
    s16x4 o;
    if (row < N_ROWS) {
        f32x4 s = {0.f, 0.f, 0.f, 0.f};
        if (KS == 16) {
            #pragma unroll
            for (int k = 0; k < 16; ++k) {
                s16x4 v = *(const s16x4*)(P + (size_t)k * MP * 256 + (size_t)row * 256 + col);
                #pragma unroll
                for (int j = 0; j < 4; ++j) s[j] += bf2f(v[j]);
            }
        } else {
            for (int k = 0; k < KS; ++k) {
                s16x4 v = *(const s16x4*)(P + (size_t)k * MP * 256 + (size_t)row * 256 + col);
                #pragma unroll
                for (int j = 0; j < 4; ++j) s[j] += bf2f(v[j]);
            }
        }
        #pragma unroll
        for (int j = 0; j < 4; ++j)
            o[j] = f2bf(fmaxf(s[j] + b1[col + j], 0.f));
    } else {
        o[0] = o[1] = o[2] = o[3] = 0;
    }
    *(s16x4*)(H + (size_t)row * 256 + col) = o;
}

// out = log_softmax(sum_s P[s] + b2) over 40 cols; P rows 64 wide (bf16)
__global__ __launch_bounds__(256)
void reduce_softmax(const short* __restrict__ P, const float* __restrict__ b2,
                    float* __restrict__ out, int KS)
{
    int lane = threadIdx.x & 63;
    int row  = blockIdx.x * 4 + (threadIdx.x >> 6);
    if (row >= N_ROWS) return;
    float v = 0.f;
    if (KS == 16) {
        #pragma unroll
        for (int k = 0; k < 16; ++k)
            v += bf2f(P[(size_t)k * MP * 64 + (size_t)row * 64 + lane]);
    } else {
        for (int k = 0; k < KS; ++k)
            v += bf2f(P[(size_t)k * MP * 64 + (size_t)row * 64 + lane]);
    }
    float vv = (lane < 40) ? v + b2[lane] : -__builtin_inff();
    float mx = vv;
    #pragma unroll
    for (int off = 1; off < 64; off <<= 1)
        mx = fmaxf(mx, __shfl_xor(mx, off));
    float e = (lane < 40) ? __expf(vv - mx) : 0.f;
    float s = e;
    #pragma unroll
    for (int off = 1; off < 64; off <<= 1)
        s += __shfl_xor(s, off);
    float lse = mx + __logf(s);
    if (lane < 40) out[(size_t)row * 40 + lane] = vv - lse;
}

// W1 [512][256] f32 -> W1t [256][512] bf16
__global__ void transpose_W1(const float* __restrict__ W1, short* __restrict__ W1t) {
    int k = blockIdx.x;      // 0..511
    int c = threadIdx.x;     // 0..255
    W1t[c * 512 + k] = f2bf(W1[k * 256 + c]);
}

// W2 [256][40] f32 -> W2t [64][256] bf16 (zero-padded cols 40..63)
__global__ void transpose_W2(const float* __restrict__ W2, short* __restrict__ W2t) {
    int k = blockIdx.x;      // 0..255
    int c = threadIdx.x;     // 0..63
    float v = (c < 40) ? W2[k * 40 + c] : 0.f;
    W2t[c * 256 + k] = f2bf(v);
}

extern "C" void kernel_launch(void* const* d_in, const int* in_sizes, int n_in,
                              void* d_out, int out_size, void* d_ws, size_t ws_size,
                              hipStream_t stream)
{
    const float* feature = (const float*)d_in[0];  // [10000,512]
    const float* adj     = (const float*)d_in[1];  // [10000,10000]
    const float* W1      = (const float*)d_in[2];  // [512,256]
    const float* b1      = (const float*)d_in[3];  // [256]
    const float* W2      = (const float*)d_in[4];  // [256,40]
    const float* b2      = (const float*)d_in[5];  // [40]
    float* out = (float*)d_out;                    // [10000,40]

    char* w = (char*)d_ws;
    short* XWt = (short*)w;  w += 256L * MP * 2;      // [256][10048] bf16
    short* H   = (short*)w;  w += (long)MP * 256 * 2; // [10048][256] bf16
    short* HWt = (short*)w;  w += 64L * MP * 2;       // [64][10048] bf16
    short* W1t = (short*)w;  w += 256L * 512 * 2;     // [256][512] bf16
    short* W2t = (short*)w;  w += 64L * 256 * 2;      // [64][256] bf16
    short* P   = (short*)w;                           // bf16 K-split partials
    size_t baseBytes = (size_t)((char*)P - (char*)d_ws);

    const size_t pbytes = (size_t)MP * 256 * 2;       // one G2 bf16 partial buffer
    int KS = 1;
    if      (ws_size >= baseBytes + 16 * pbytes) KS = 16;
    else if (ws_size >= baseBytes +  8 * pbytes) KS = 8;
    else if (ws_size >= baseBytes +  4 * pbytes) KS = 4;
    else if (ws_size >= baseBytes +  2 * pbytes) KS = 2;

    transpose_W1<<<512, 256, 0, stream>>>(W1, W1t);
    transpose_W2<<<256, 64, 0, stream>>>(W2, W2t);

    // G1: XW = feature @ W1 -> XWt (transposed store)
    gemm_k<64, 256, 2, 4, 1, 0><<<157, 512, 0, stream>>>(
        feature, 512, N_ROWS, 512, W1t, 512, 8, XWt, MP, MP, nullptr, 8);

    if (KS > 1) {
        int KTS = (157 + KS - 1) / KS;
        // G2: bf16 partials = adj @ XW (K-split)
        gemm_k<64, 256, 2, 4, 1, 3><<<dim3(157, KS), 512, 0, stream>>>(
            adj, N_ROWS, N_ROWS, N_ROWS, XWt, MP, 157, P, 256, MP, nullptr, KTS);
        // R1: H = relu(sum + b1)
        reduce_relu<<<MP * 256 / 4 / 256, 256, 0, stream>>>(P, b1, H, KS);
        // G3: HW = H @ W2 -> HWt
        gemm_k<64, 64, 4, 2, 0, 0><<<157, 512, 0, stream>>>(
            H, 256, MP, 256, W2t, 256, 4, HWt, MP, MP, nullptr, 4);
        // G4: bf16 partials = adj @ HW (K-split)
        gemm_k<64, 64, 4, 2, 1, 3><<<dim3(157, KS), 512, 0, stream>>>(
            adj, N_ROWS, N_ROWS, N_ROWS, HWt, MP, 157, P, 64, MP, nullptr, KTS);
        // R2: out = log_softmax(sum + b2)
        reduce_softmax<<<2500, 256, 0, stream>>>(P, b2, out, KS);
    } else {
        // fallback: no split (round-0 behavior)
        gemm_k<64, 256, 2, 4, 1, 1><<<157, 512, 0, stream>>>(
            adj, N_ROWS, N_ROWS, N_ROWS, XWt, MP, 157, H, 256, MP, b1, 157);
        gemm_k<64, 64, 4, 2, 0, 0><<<157, 512, 0, stream>>>(
            H, 256, MP, 256, W2t, 256, 4, HWt, MP, MP, nullptr, 4);
        gemm_k<128, 64, 8, 1, 1, 2><<<79, 512, 0, stream>>>(
            adj, N_ROWS, N_ROWS, N_ROWS, HWt, MP, 157, out, 40, N_ROWS, b2, 157);
    }
}

// Round 7
// 258.405 us; speedup vs baseline: 1.7053x; 1.0053x over previous
//
#include <hip/hip_runtime.h>
#include <hip/hip_bf16.h>

typedef short s16x8 __attribute__((ext_vector_type(8)));
typedef short s16x4 __attribute__((ext_vector_type(4)));
typedef float f32x4 __attribute__((ext_vector_type(4)));

#define N_ROWS 10000
#define MP 10048   // padded M/K for adj dim (157*64)

// native RNE f32->bf16 (compiler emits v_cvt_pk_bf16_f32 for pairs; m240)
__device__ inline short f2bf(float f) {
    __hip_bfloat16 h = __float2bfloat16(f);
    return __builtin_bit_cast(short, h);
}
__device__ inline float bf2f(short b) {
    return __builtin_bit_cast(float, ((unsigned)(unsigned short)b) << 16);
}

// swizzled LDS index (units: bf16 elements, rows of 64)
__device__ inline int swz(int row, int col) {
    return (row * 64 + col) ^ ((row & 7) << 3);
}

// ---------------------------------------------------------------------------
// Unified MFMA GEMM with depth-1 register prefetch (round-3 structure).
//  C[M x BN] = A[M x K] * B[K x BN]
//  A: row-major, f32 (AF32=1, converted on the fly) or bf16 bits (AF32=0)
//  B: given TRANSPOSED as Bt[BN][ldBt] bf16 bits (row n = column n of B)
//  K-split: blockIdx.y picks tile range [y*ktPerSplit, min(+ktPerSplit,Ktiles))
//  EPI 0: store C^T bf16 -> Cp[gc*ldC + gm]
//  EPI 1: store relu(C + bias) bf16 row-major -> Cp[gm*ldC + gc]
//  EPI 2: logits = C + bias; row log_softmax; store f32 -> Cp[gm*ldC+gc], gc<40
//  EPI 3: store bf16 partial -> ((short*)Cp + y*MP*BN)[gm*BN + gc]
// ---------------------------------------------------------------------------
template<int BM, int BN, int WM, int WN, int AF32, int EPI>
__global__ __launch_bounds__(512)
void gemm_k(const void* __restrict__ Ap, int ldA, int Mval, int Kval,
            const short* __restrict__ Bt, int ldBt, int Ktiles,
            void* __restrict__ Cp, int ldC, int Cval,
            const float* __restrict__ bias, int ktPerSplit)
{
    constexpr int WTM = BM / WM, WTN = BN / WN;
    constexpr int M_rep = WTM / 16, N_rep = WTN / 16;
    constexpr int AREP = BM / 64, BREP = BN / 64;

    __shared__ alignas(16) short Alds[BM * 64];
    __shared__ alignas(16) short Blds[BN * 64];

    const int tid  = threadIdx.x;
    const int lane = tid & 63;
    const int w    = tid >> 6;
    const int wr   = w / WN, wc = w % WN;
    const int m0   = blockIdx.x * BM;

    // prefetch registers (statically indexed via unrolled loops)
    float4 va0[AREP], va1[AREP];
    s16x8  vab[AREP];
    s16x8  vb[BREP];

    auto load_regs = [&](int kt) {
        const int k0 = kt * 64;
        #pragma unroll
        for (int rep = 0; rep < AREP; ++rep) {
            int e   = tid + rep * 512;
            int row = e >> 3, cc = (e & 7) * 8;
            int gm  = m0 + row, gk = k0 + cc;
            if constexpr (AF32) {
                float4 z = {0.f, 0.f, 0.f, 0.f};
                va0[rep] = z; va1[rep] = z;
                if (gm < Mval && gk < Kval) {
                    const float* p = (const float*)Ap + (long)gm * ldA + gk;
                    va0[rep] = *(const float4*)p;
                    va1[rep] = *(const float4*)(p + 4);
                }
            } else {
                if (gm < Mval && gk < Kval) {
                    vab[rep] = *(const s16x8*)((const short*)Ap + (long)gm * ldA + gk);
                } else {
                    s16x8 z;
                    #pragma unroll
                    for (int j = 0; j < 8; ++j) z[j] = 0;
                    vab[rep] = z;
                }
            }
        }
        #pragma unroll
        for (int rep = 0; rep < BREP; ++rep) {
            int e   = tid + rep * 512;
            int row = e >> 3, cc = (e & 7) * 8;
            vb[rep] = *(const s16x8*)(Bt + (long)row * ldBt + k0 + cc);
        }
    };

    auto write_lds = [&]() {
        #pragma unroll
        for (int rep = 0; rep < AREP; ++rep) {
            int e   = tid + rep * 512;
            int row = e >> 3, cc = (e & 7) * 8;
            s16x8 b;
            if constexpr (AF32) {
                b[0]=f2bf(va0[rep].x); b[1]=f2bf(va0[rep].y);
                b[2]=f2bf(va0[rep].z); b[3]=f2bf(va0[rep].w);
                b[4]=f2bf(va1[rep].x); b[5]=f2bf(va1[rep].y);
                b[6]=f2bf(va1[rep].z); b[7]=f2bf(va1[rep].w);
            } else {
                b = vab[rep];
            }
            *(s16x8*)(&Alds[swz(row, cc)]) = b;
        }
        #pragma unroll
        for (int rep = 0; rep < BREP; ++rep) {
            int e   = tid + rep * 512;
            int row = e >> 3, cc = (e & 7) * 8;
            *(s16x8*)(&Blds[swz(row, cc)]) = vb[rep];
        }
    };

    f32x4 acc[M_rep][N_rep];
    const f32x4 zero4 = {0.f, 0.f, 0.f, 0.f};
    #pragma unroll
    for (int mi = 0; mi < M_rep; ++mi)
        #pragma unroll
        for (int nj = 0; nj < N_rep; ++nj) acc[mi][nj] = zero4;

    const int kt0 = blockIdx.y * ktPerSplit;
    int ktEnd = kt0 + ktPerSplit;
    if (ktEnd > Ktiles) ktEnd = Ktiles;

    // prologue: stage first tile
    load_regs(kt0);
    write_lds();

    for (int kt = kt0; kt < ktEnd; ++kt) {
        __syncthreads();                       // staged tile visible
        if (kt + 1 < ktEnd) load_regs(kt + 1); // issue next loads (hide under compute)
        // ---- compute tile kt ----
        #pragma unroll
        for (int kk = 0; kk < 2; ++kk) {
            const int krd = kk * 32 + (lane >> 4) * 8;
            s16x8 af[M_rep], bf[N_rep];
            #pragma unroll
            for (int mi = 0; mi < M_rep; ++mi) {
                int row = wr * WTM + mi * 16 + (lane & 15);
                af[mi] = *(const s16x8*)(&Alds[swz(row, krd)]);
            }
            #pragma unroll
            for (int nj = 0; nj < N_rep; ++nj) {
                int row = wc * WTN + nj * 16 + (lane & 15);
                bf[nj] = *(const s16x8*)(&Blds[swz(row, krd)]);
            }
            #pragma unroll
            for (int mi = 0; mi < M_rep; ++mi)
                #pragma unroll
                for (int nj = 0; nj < N_rep; ++nj)
                    acc[mi][nj] = __builtin_amdgcn_mfma_f32_16x16x32_bf16(
                        af[mi], bf[nj], acc[mi][nj], 0, 0, 0);
        }
        __syncthreads();                       // all reads done before overwrite
        if (kt + 1 < ktEnd) write_lds();       // vmcnt wait happens here
    }

    // ---- epilogue ----
    const int mbase = m0 + wr * WTM;
    if constexpr (EPI == 0) {
        short* CT = (short*)Cp;
        #pragma unroll
        for (int mi = 0; mi < M_rep; ++mi) {
            int gm = mbase + mi * 16 + (lane >> 4) * 4;
            if (gm >= Cval) continue;
            #pragma unroll
            for (int nj = 0; nj < N_rep; ++nj) {
                int gc = wc * WTN + nj * 16 + (lane & 15);
                s16x4 p;
                #pragma unroll
                for (int r = 0; r < 4; ++r) p[r] = f2bf(acc[mi][nj][r]);
                *(s16x4*)(CT + (long)gc * ldC + gm) = p;
            }
        }
    } else if constexpr (EPI == 1) {
        short* C = (short*)Cp;
        #pragma unroll
        for (int nj = 0; nj < N_rep; ++nj) {
            int gc = wc * WTN + nj * 16 + (lane & 15);
            float b = bias[gc];
            #pragma unroll
            for (int mi = 0; mi < M_rep; ++mi) {
                int gm = mbase + mi * 16 + (lane >> 4) * 4;
                #pragma unroll
                for (int r = 0; r < 4; ++r) {
                    float v = acc[mi][nj][r] + b;
                    v = fmaxf(v, 0.f);
                    C[(long)(gm + r) * ldC + gc] = f2bf(v);
                }
            }
        }
    } else if constexpr (EPI == 2) {
        // requires WN==1, M_rep==1, N_rep==4 (BN=64 covers all cols)
        float* out = (float*)Cp;
        const int gmb = mbase + (lane >> 4) * 4;
        #pragma unroll
        for (int r = 0; r < 4; ++r) {
            float v[4];
            float mx = -__builtin_inff();
            #pragma unroll
            for (int nj = 0; nj < 4; ++nj) {
                int gc = nj * 16 + (lane & 15);
                float vv = -__builtin_inff();
                if (gc < 40) vv = acc[0][nj][r] + bias[gc];
                v[nj] = vv;
                mx = fmaxf(mx, vv);
            }
            #pragma unroll
            for (int off = 1; off < 16; off <<= 1)
                mx = fmaxf(mx, __shfl_xor(mx, off));
            float s = 0.f;
            #pragma unroll
            for (int nj = 0; nj < 4; ++nj)
                s += (v[nj] == -__builtin_inff()) ? 0.f : __expf(v[nj] - mx);
            #pragma unroll
            for (int off = 1; off < 16; off <<= 1)
                s += __shfl_xor(s, off);
            float lse = mx + __logf(s);
            int gm = gmb + r;
            if (gm < Cval) {
                #pragma unroll
                for (int nj = 0; nj < 4; ++nj) {
                    int gc = nj * 16 + (lane & 15);
                    if (gc < 40) out[(long)gm * ldC + gc] = v[nj] - lse;
                }
            }
        }
    } else {
        // EPI == 3: bf16 partial store, one buffer per K-split
        short* Cpart = (short*)Cp + (size_t)blockIdx.y * MP * BN;
        #pragma unroll
        for (int nj = 0; nj < N_rep; ++nj) {
            int gc = wc * WTN + nj * 16 + (lane & 15);
            #pragma unroll
            for (int mi = 0; mi < M_rep; ++mi) {
                int gm = mbase + mi * 16 + (lane >> 4) * 4;
                #pragma unroll
                for (int r = 0; r < 4; ++r)
                    Cpart[(long)(gm + r) * BN + gc] = f2bf(acc[mi][nj][r]);
            }
        }
    }
}

// H = relu(sum_s P[s] + b1), bf16 [MP][256]; pad rows -> 0. P: bf16 partials.
// one s16x8 chunk (8 cols) per thread
__global__ __launch_bounds__(256)
void reduce_relu(const short* __restrict__ P, const float* __restrict__ b1,
                 short* __restrict__ H, int KS)
{
    int idx8 = blockIdx.x * 256 + threadIdx.x;
    int row  = idx8 >> 5;                        // 32 chunks per 256-wide row
    int col  = (idx8 & 31) * 8;
    s16x8 o;
    if (row < N_ROWS) {
        float s[8] = {0,0,0,0,0,0,0,0};
        if (KS == 16) {
            #pragma unroll
            for (int k = 0; k < 16; ++k) {
                s16x8 v = *(const s16x8*)(P + (size_t)k * MP * 256 + (size_t)row * 256 + col);
                #pragma unroll
                for (int j = 0; j < 8; ++j) s[j] += bf2f(v[j]);
            }
        } else {
            for (int k = 0; k < KS; ++k) {
                s16x8 v = *(const s16x8*)(P + (size_t)k * MP * 256 + (size_t)row * 256 + col);
                #pragma unroll
                for (int j = 0; j < 8; ++j) s[j] += bf2f(v[j]);
            }
        }
        #pragma unroll
        for (int j = 0; j < 8; ++j)
            o[j] = f2bf(fmaxf(s[j] + b1[col + j], 0.f));
    } else {
        #pragma unroll
        for (int j = 0; j < 8; ++j) o[j] = 0;
    }
    *(s16x8*)(H + (size_t)row * 256 + col) = o;
}

// out = log_softmax(sum_s P[s] + b2) over 40 cols; P rows 64 wide (bf16)
__global__ __launch_bounds__(256)
void reduce_softmax(const short* __restrict__ P, const float* __restrict__ b2,
                    float* __restrict__ out, int KS)
{
    int lane = threadIdx.x & 63;
    int row  = blockIdx.x * 4 + (threadIdx.x >> 6);
    if (row >= N_ROWS) return;
    float v = 0.f;
    if (KS == 16) {
        #pragma unroll
        for (int k = 0; k < 16; ++k)
            v += bf2f(P[(size_t)k * MP * 64 + (size_t)row * 64 + lane]);
    } else {
        for (int k = 0; k < KS; ++k)
            v += bf2f(P[(size_t)k * MP * 64 + (size_t)row * 64 + lane]);
    }
    float vv = (lane < 40) ? v + b2[lane] : -__builtin_inff();
    float mx = vv;
    #pragma unroll
    for (int off = 1; off < 64; off <<= 1)
        mx = fmaxf(mx, __shfl_xor(mx, off));
    float e = (lane < 40) ? __expf(vv - mx) : 0.f;
    float s = e;
    #pragma unroll
    for (int off = 1; off < 64; off <<= 1)
        s += __shfl_xor(s, off);
    float lse = mx + __logf(s);
    if (lane < 40) out[(size_t)row * 40 + lane] = vv - lse;
}

// merged weight prep:
//  blocks 0..511:  W1 [512][256] -> W1t [256][512]
//  blocks 512..767: W2 [256][40] -> W2t [64][256] (zero-padded cols 40..63)
__global__ __launch_bounds__(256)
void prep_w(const float* __restrict__ W1, const float* __restrict__ W2,
            short* __restrict__ W1t, short* __restrict__ W2t)
{
    int bid = blockIdx.x, c = threadIdx.x;
    if (bid < 512) {
        W1t[c * 512 + bid] = f2bf(W1[bid * 256 + c]);
    } else {
        int k = bid - 512;
        if (c < 64) {
            float v = (c < 40) ? W2[k * 40 + c] : 0.f;
            W2t[c * 256 + k] = f2bf(v);
        }
    }
}

extern "C" void kernel_launch(void* const* d_in, const int* in_sizes, int n_in,
                              void* d_out, int out_size, void* d_ws, size_t ws_size,
                              hipStream_t stream)
{
    const float* feature = (const float*)d_in[0];  // [10000,512]
    const float* adj     = (const float*)d_in[1];  // [10000,10000]
    const float* W1      = (const float*)d_in[2];  // [512,256]
    const float* b1      = (const float*)d_in[3];  // [256]
    const float* W2      = (const float*)d_in[4];  // [256,40]
    const float* b2      = (const float*)d_in[5];  // [40]
    float* out = (float*)d_out;                    // [10000,40]

    char* w = (char*)d_ws;
    short* XWt = (short*)w;  w += 256L * MP * 2;      // [256][10048] bf16
    short* H   = (short*)w;  w += (long)MP * 256 * 2; // [10048][256] bf16
    short* HWt = (short*)w;  w += 64L * MP * 2;       // [64][10048] bf16
    short* W1t = (short*)w;  w += 256L * 512 * 2;     // [256][512] bf16
    short* W2t = (short*)w;  w += 64L * 256 * 2;      // [64][256] bf16
    short* P   = (short*)w;                           // bf16 K-split partials
    size_t baseBytes = (size_t)((char*)P - (char*)d_ws);

    const size_t pbytes = (size_t)MP * 256 * 2;       // one G2 bf16 partial buffer
    int KS = 1;
    if      (ws_size >= baseBytes + 16 * pbytes) KS = 16;
    else if (ws_size >= baseBytes +  8 * pbytes) KS = 8;
    else if (ws_size >= baseBytes +  4 * pbytes) KS = 4;
    else if (ws_size >= baseBytes +  2 * pbytes) KS = 2;

    prep_w<<<768, 256, 0, stream>>>(W1, W2, W1t, W2t);

    // G1: XW = feature @ W1 -> XWt (transposed store)
    gemm_k<64, 256, 2, 4, 1, 0><<<157, 512, 0, stream>>>(
        feature, 512, N_ROWS, 512, W1t, 512, 8, XWt, MP, MP, nullptr, 8);

    if (KS > 1) {
        int KTS = (157 + KS - 1) / KS;
        // G2: bf16 partials = adj @ XW (K-split)
        gemm_k<64, 256, 2, 4, 1, 3><<<dim3(157, KS), 512, 0, stream>>>(
            adj, N_ROWS, N_ROWS, N_ROWS, XWt, MP, 157, P, 256, MP, nullptr, KTS);
        // R1: H = relu(sum + b1)
        reduce_relu<<<MP / 8, 256, 0, stream>>>(P, b1, H, KS);
        // G3: HW = H @ W2 -> HWt
        gemm_k<64, 64, 4, 2, 0, 0><<<157, 512, 0, stream>>>(
            H, 256, MP, 256, W2t, 256, 4, HWt, MP, MP, nullptr, 4);
        // G4: bf16 partials = adj @ HW (K-split)
        gemm_k<64, 64, 4, 2, 1, 3><<<dim3(157, KS), 512, 0, stream>>>(
            adj, N_ROWS, N_ROWS, N_ROWS, HWt, MP, 157, P, 64, MP, nullptr, KTS);
        // R2: out = log_softmax(sum + b2)
        reduce_softmax<<<2500, 256, 0, stream>>>(P, b2, out, KS);
    } else {
        // fallback: no split (round-0 behavior)
        gemm_k<64, 256, 2, 4, 1, 1><<<157, 512, 0, stream>>>(
            adj, N_ROWS, N_ROWS, N_ROWS, XWt, MP, 157, H, 256, MP, b1, 157);
        gemm_k<64, 64, 4, 2, 0, 0><<<157, 512, 0, stream>>>(
            H, 256, MP, 256, W2t, 256, 4, HWt, MP, MP, nullptr, 4);
        gemm_k<128, 64, 8, 1, 1, 2><<<79, 512, 0, stream>>>(
            adj, N_ROWS, N_ROWS, N_ROWS, HWt, MP, 157, out, 40, N_ROWS, b2, 157);
    }
}

// Round 8
// 249.362 us; speedup vs baseline: 1.7672x; 1.0363x over previous
//
#include <hip/hip_runtime.h>
#include <hip/hip_bf16.h>

typedef short s16x8 __attribute__((ext_vector_type(8)));
typedef short s16x4 __attribute__((ext_vector_type(4)));
typedef float f32x4 __attribute__((ext_vector_type(4)));

#define N_ROWS 10000
#define MP   10048   // padded adj dim (157*64)
#define MPAD 10112   // partial-buffer row stride (79*128, covers BM=128 grids)

// native RNE f32->bf16 (compiler emits v_cvt_pk_bf16_f32 for pairs)
__device__ inline short f2bf(float f) {
    __hip_bfloat16 h = __float2bfloat16(f);
    return __builtin_bit_cast(short, h);
}
__device__ inline float bf2f(short b) {
    return __builtin_bit_cast(float, ((unsigned)(unsigned short)b) << 16);
}

// swizzled LDS index (units: bf16 elements, rows of 64)
__device__ inline int swz(int row, int col) {
    return (row * 64 + col) ^ ((row & 7) << 3);
}

// ---------------------------------------------------------------------------
// Unified MFMA GEMM with depth-1 register prefetch.
//  C[M x BN] = A[M x K] * B[K x BN]
//  A: row-major, f32 (AF32=1, converted on the fly) or bf16 bits (AF32=0)
//  B: TRANSPOSED as Bt[BN][ldBt] bf16 bits (row n = column n of B)
//  K-split: blockIdx.y picks tile range [y*ktPerSplit, min(+ktPerSplit,Ktiles))
//  EPI 0: store C^T bf16 -> Cp[gc*ldC + gm]
//  EPI 1: store relu(C + bias) bf16 row-major -> Cp[gm*ldC + gc]
//  EPI 2: logits = C + bias; row log_softmax; store f32 -> Cp[gm*ldC+gc], gc<40
//  EPI 3: store bf16 partial -> ((short*)Cp + y*ldC*BN)[gm*BN + gc]  (ldC=row stride)
// ---------------------------------------------------------------------------
template<int BM, int BN, int WM, int WN, int AF32, int EPI>
__global__ __launch_bounds__(512)
void gemm_k(const void* __restrict__ Ap, int ldA, int Mval, int Kval,
            const short* __restrict__ Bt, int ldBt, int Ktiles,
            void* __restrict__ Cp, int ldC, int Cval,
            const float* __restrict__ bias, int ktPerSplit)
{
    constexpr int WTM = BM / WM, WTN = BN / WN;
    constexpr int M_rep = WTM / 16, N_rep = WTN / 16;
    constexpr int AREP = BM / 64, BREP = BN / 64;

    __shared__ alignas(16) short Alds[BM * 64];
    __shared__ alignas(16) short Blds[BN * 64];

    const int tid  = threadIdx.x;
    const int lane = tid & 63;
    const int w    = tid >> 6;
    const int wr   = w / WN, wc = w % WN;
    const int m0   = blockIdx.x * BM;

    float4 va0[AREP], va1[AREP];
    s16x8  vab[AREP];
    s16x8  vb[BREP];

    auto load_regs = [&](int kt) {
        const int k0 = kt * 64;
        #pragma unroll
        for (int rep = 0; rep < AREP; ++rep) {
            int e   = tid + rep * 512;
            int row = e >> 3, cc = (e & 7) * 8;
            int gm  = m0 + row, gk = k0 + cc;
            if constexpr (AF32) {
                float4 z = {0.f, 0.f, 0.f, 0.f};
                va0[rep] = z; va1[rep] = z;
                if (gm < Mval && gk < Kval) {
                    const float* p = (const float*)Ap + (long)gm * ldA + gk;
                    va0[rep] = *(const float4*)p;
                    va1[rep] = *(const float4*)(p + 4);
                }
            } else {
                if (gm < Mval && gk < Kval) {
                    vab[rep] = *(const s16x8*)((const short*)Ap + (long)gm * ldA + gk);
                } else {
                    s16x8 z;
                    #pragma unroll
                    for (int j = 0; j < 8; ++j) z[j] = 0;
                    vab[rep] = z;
                }
            }
        }
        #pragma unroll
        for (int rep = 0; rep < BREP; ++rep) {
            int e   = tid + rep * 512;
            int row = e >> 3, cc = (e & 7) * 8;
            vb[rep] = *(const s16x8*)(Bt + (long)row * ldBt + k0 + cc);
        }
    };

    auto write_lds = [&]() {
        #pragma unroll
        for (int rep = 0; rep < AREP; ++rep) {
            int e   = tid + rep * 512;
            int row = e >> 3, cc = (e & 7) * 8;
            s16x8 b;
            if constexpr (AF32) {
                b[0]=f2bf(va0[rep].x); b[1]=f2bf(va0[rep].y);
                b[2]=f2bf(va0[rep].z); b[3]=f2bf(va0[rep].w);
                b[4]=f2bf(va1[rep].x); b[5]=f2bf(va1[rep].y);
                b[6]=f2bf(va1[rep].z); b[7]=f2bf(va1[rep].w);
            } else {
                b = vab[rep];
            }
            *(s16x8*)(&Alds[swz(row, cc)]) = b;
        }
        #pragma unroll
        for (int rep = 0; rep < BREP; ++rep) {
            int e   = tid + rep * 512;
            int row = e >> 3, cc = (e & 7) * 8;
            *(s16x8*)(&Blds[swz(row, cc)]) = vb[rep];
        }
    };

    f32x4 acc[M_rep][N_rep];
    const f32x4 zero4 = {0.f, 0.f, 0.f, 0.f};
    #pragma unroll
    for (int mi = 0; mi < M_rep; ++mi)
        #pragma unroll
        for (int nj = 0; nj < N_rep; ++nj) acc[mi][nj] = zero4;

    const int kt0 = blockIdx.y * ktPerSplit;
    int ktEnd = kt0 + ktPerSplit;
    if (ktEnd > Ktiles) ktEnd = Ktiles;

    load_regs(kt0);
    write_lds();

    for (int kt = kt0; kt < ktEnd; ++kt) {
        __syncthreads();
        if (kt + 1 < ktEnd) load_regs(kt + 1);
        #pragma unroll
        for (int kk = 0; kk < 2; ++kk) {
            const int krd = kk * 32 + (lane >> 4) * 8;
            s16x8 af[M_rep], bf[N_rep];
            #pragma unroll
            for (int mi = 0; mi < M_rep; ++mi) {
                int row = wr * WTM + mi * 16 + (lane & 15);
                af[mi] = *(const s16x8*)(&Alds[swz(row, krd)]);
            }
            #pragma unroll
            for (int nj = 0; nj < N_rep; ++nj) {
                int row = wc * WTN + nj * 16 + (lane & 15);
                bf[nj] = *(const s16x8*)(&Blds[swz(row, krd)]);
            }
            #pragma unroll
            for (int mi = 0; mi < M_rep; ++mi)
                #pragma unroll
                for (int nj = 0; nj < N_rep; ++nj)
                    acc[mi][nj] = __builtin_amdgcn_mfma_f32_16x16x32_bf16(
                        af[mi], bf[nj], acc[mi][nj], 0, 0, 0);
        }
        __syncthreads();
        if (kt + 1 < ktEnd) write_lds();
    }

    // ---- epilogue ----
    const int mbase = m0 + wr * WTM;
    if constexpr (EPI == 0) {
        short* CT = (short*)Cp;
        #pragma unroll
        for (int mi = 0; mi < M_rep; ++mi) {
            int gm = mbase + mi * 16 + (lane >> 4) * 4;
            if (gm >= Cval) continue;
            #pragma unroll
            for (int nj = 0; nj < N_rep; ++nj) {
                int gc = wc * WTN + nj * 16 + (lane & 15);
                s16x4 p;
                #pragma unroll
                for (int r = 0; r < 4; ++r) p[r] = f2bf(acc[mi][nj][r]);
                *(s16x4*)(CT + (long)gc * ldC + gm) = p;
            }
        }
    } else if constexpr (EPI == 1) {
        short* C = (short*)Cp;
        #pragma unroll
        for (int nj = 0; nj < N_rep; ++nj) {
            int gc = wc * WTN + nj * 16 + (lane & 15);
            float b = bias[gc];
            #pragma unroll
            for (int mi = 0; mi < M_rep; ++mi) {
                int gm = mbase + mi * 16 + (lane >> 4) * 4;
                #pragma unroll
                for (int r = 0; r < 4; ++r) {
                    float v = acc[mi][nj][r] + b;
                    v = fmaxf(v, 0.f);
                    C[(long)(gm + r) * ldC + gc] = f2bf(v);
                }
            }
        }
    } else if constexpr (EPI == 2) {
        float* out = (float*)Cp;
        const int gmb = mbase + (lane >> 4) * 4;
        #pragma unroll
        for (int r = 0; r < 4; ++r) {
            float v[4];
            float mx = -__builtin_inff();
            #pragma unroll
            for (int nj = 0; nj < 4; ++nj) {
                int gc = nj * 16 + (lane & 15);
                float vv = -__builtin_inff();
                if (gc < 40) vv = acc[0][nj][r] + bias[gc];
                v[nj] = vv;
                mx = fmaxf(mx, vv);
            }
            #pragma unroll
            for (int off = 1; off < 16; off <<= 1)
                mx = fmaxf(mx, __shfl_xor(mx, off));
            float s = 0.f;
            #pragma unroll
            for (int nj = 0; nj < 4; ++nj)
                s += (v[nj] == -__builtin_inff()) ? 0.f : __expf(v[nj] - mx);
            #pragma unroll
            for (int off = 1; off < 16; off <<= 1)
                s += __shfl_xor(s, off);
            float lse = mx + __logf(s);
            int gm = gmb + r;
            if (gm < Cval) {
                #pragma unroll
                for (int nj = 0; nj < 4; ++nj) {
                    int gc = nj * 16 + (lane & 15);
                    if (gc < 40) out[(long)gm * ldC + gc] = v[nj] - lse;
                }
            }
        }
    } else {
        // EPI == 3: bf16 partial store; ldC = partial row stride (MPAD)
        short* Cpart = (short*)Cp + (size_t)blockIdx.y * ldC * BN;
        #pragma unroll
        for (int nj = 0; nj < N_rep; ++nj) {
            int gc = wc * WTN + nj * 16 + (lane & 15);
            #pragma unroll
            for (int mi = 0; mi < M_rep; ++mi) {
                int gm = mbase + mi * 16 + (lane >> 4) * 4;
                #pragma unroll
                for (int r = 0; r < 4; ++r)
                    Cpart[(long)(gm + r) * BN + gc] = f2bf(acc[mi][nj][r]);
            }
        }
    }
}

// H = relu(sum_s P[s] + b1), bf16 [MP][256]; pad rows -> 0. P: bf16 partials.
__global__ __launch_bounds__(256)
void reduce_relu(const short* __restrict__ P, const float* __restrict__ b1,
                 short* __restrict__ H, int KS)
{
    int idx8 = blockIdx.x * 256 + threadIdx.x;
    int row  = idx8 >> 5;
    int col  = (idx8 & 31) * 8;
    s16x8 o;
    if (row < N_ROWS) {
        float s[8] = {0,0,0,0,0,0,0,0};
        if (KS == 8) {
            #pragma unroll
            for (int k = 0; k < 8; ++k) {
                s16x8 v = *(const s16x8*)(P + (size_t)k * MPAD * 256 + (size_t)row * 256 + col);
                #pragma unroll
                for (int j = 0; j < 8; ++j) s[j] += bf2f(v[j]);
            }
        } else {
            for (int k = 0; k < KS; ++k) {
                s16x8 v = *(const s16x8*)(P + (size_t)k * MPAD * 256 + (size_t)row * 256 + col);
                #pragma unroll
                for (int j = 0; j < 8; ++j) s[j] += bf2f(v[j]);
            }
        }
        #pragma unroll
        for (int j = 0; j < 8; ++j)
            o[j] = f2bf(fmaxf(s[j] + b1[col + j], 0.f));
    } else {
        #pragma unroll
        for (int j = 0; j < 8; ++j) o[j] = 0;
    }
    *(s16x8*)(H + (size_t)row * 256 + col) = o;
}

// out = log_softmax(sum_s P[s] + b2) over 40 cols; P rows 64 wide (bf16)
__global__ __launch_bounds__(256)
void reduce_softmax(const short* __restrict__ P, const float* __restrict__ b2,
                    float* __restrict__ out, int KS)
{
    int lane = threadIdx.x & 63;
    int row  = blockIdx.x * 4 + (threadIdx.x >> 6);
    if (row >= N_ROWS) return;
    float v = 0.f;
    if (KS == 16) {
        #pragma unroll
        for (int k = 0; k < 16; ++k)
            v += bf2f(P[(size_t)k * MPAD * 64 + (size_t)row * 64 + lane]);
    } else {
        for (int k = 0; k < KS; ++k)
            v += bf2f(P[(size_t)k * MPAD * 64 + (size_t)row * 64 + lane]);
    }
    float vv = (lane < 40) ? v + b2[lane] : -__builtin_inff();
    float mx = vv;
    #pragma unroll
    for (int off = 1; off < 64; off <<= 1)
        mx = fmaxf(mx, __shfl_xor(mx, off));
    float e = (lane < 40) ? __expf(vv - mx) : 0.f;
    float s = e;
    #pragma unroll
    for (int off = 1; off < 64; off <<= 1)
        s += __shfl_xor(s, off);
    float lse = mx + __logf(s);
    if (lane < 40) out[(size_t)row * 40 + lane] = vv - lse;
}

// merged weight prep
__global__ __launch_bounds__(256)
void prep_w(const float* __restrict__ W1, const float* __restrict__ W2,
            short* __restrict__ W1t, short* __restrict__ W2t)
{
    int bid = blockIdx.x, c = threadIdx.x;
    if (bid < 512) {
        W1t[c * 512 + bid] = f2bf(W1[bid * 256 + c]);
    } else {
        int k = bid - 512;
        if (c < 64) {
            float v = (c < 40) ? W2[k * 40 + c] : 0.f;
            W2t[c * 256 + k] = f2bf(v);
        }
    }
}

extern "C" void kernel_launch(void* const* d_in, const int* in_sizes, int n_in,
                              void* d_out, int out_size, void* d_ws, size_t ws_size,
                              hipStream_t stream)
{
    const float* feature = (const float*)d_in[0];  // [10000,512]
    const float* adj     = (const float*)d_in[1];  // [10000,10000]
    const float* W1      = (const float*)d_in[2];  // [512,256]
    const float* b1      = (const float*)d_in[3];  // [256]
    const float* W2      = (const float*)d_in[4];  // [256,40]
    const float* b2      = (const float*)d_in[5];  // [40]
    float* out = (float*)d_out;                    // [10000,40]

    char* w = (char*)d_ws;
    short* XWt = (short*)w;  w += 256L * MP * 2;      // [256][10048] bf16
    short* H   = (short*)w;  w += (long)MP * 256 * 2; // [10048][256] bf16
    short* HWt = (short*)w;  w += 64L * MP * 2;       // [64][10048] bf16
    short* W1t = (short*)w;  w += 256L * 512 * 2;     // [256][512] bf16
    short* W2t = (short*)w;  w += 64L * 256 * 2;      // [64][256] bf16
    short* P   = (short*)w;                           // bf16 K-split partials
    size_t baseBytes = (size_t)((char*)P - (char*)d_ws);

    const size_t p2 = (size_t)MPAD * 256 * 2;   // one G2 partial buffer
    const size_t p4 = (size_t)MPAD * 64 * 2;    // one G4 partial buffer

    prep_w<<<768, 256, 0, stream>>>(W1, W2, W1t, W2t);

    // G1: XW = feature @ W1 -> XWt (transposed store)
    gemm_k<64, 256, 2, 4, 1, 0><<<157, 512, 0, stream>>>(
        feature, 512, N_ROWS, 512, W1t, 512, 8, XWt, MP, MP, nullptr, 8);

    size_t needFull = 8 * p2 > 16 * p4 ? 8 * p2 : 16 * p4;
    if (ws_size >= baseBytes + needFull) {
        // G2: bf16 partials = adj @ XW, KS=8
        gemm_k<64, 256, 2, 4, 1, 3><<<dim3(157, 8), 512, 0, stream>>>(
            adj, N_ROWS, N_ROWS, N_ROWS, XWt, MP, 157, P, MPAD, MP, nullptr, 20);
        // R1: H = relu(sum + b1)
        reduce_relu<<<MP / 8, 256, 0, stream>>>(P, b1, H, 8);
        // G3: HW = H @ W2 -> HWt
        gemm_k<64, 64, 4, 2, 0, 0><<<157, 512, 0, stream>>>(
            H, 256, MP, 256, W2t, 256, 4, HWt, MP, MP, nullptr, 4);
        // G4: bf16 partials = adj @ HW, KS=16, BM=128
        gemm_k<128, 64, 4, 2, 1, 3><<<dim3(79, 16), 512, 0, stream>>>(
            adj, N_ROWS, N_ROWS, N_ROWS, HWt, MP, 157, P, MPAD, MP, nullptr, 10);
        // R2: out = log_softmax(sum + b2)
        reduce_softmax<<<2500, 256, 0, stream>>>(P, b2, out, 16);
    } else if (ws_size >= baseBytes + 4 * p2) {
        // reduced split fallback (KS=4 both)
        gemm_k<64, 256, 2, 4, 1, 3><<<dim3(157, 4), 512, 0, stream>>>(
            adj, N_ROWS, N_ROWS, N_ROWS, XWt, MP, 157, P, MPAD, MP, nullptr, 40);
        reduce_relu<<<MP / 8, 256, 0, stream>>>(P, b1, H, 4);
        gemm_k<64, 64, 4, 2, 0, 0><<<157, 512, 0, stream>>>(
            H, 256, MP, 256, W2t, 256, 4, HWt, MP, MP, nullptr, 4);
        gemm_k<128, 64, 4, 2, 1, 3><<<dim3(79, 4), 512, 0, stream>>>(
            adj, N_ROWS, N_ROWS, N_ROWS, HWt, MP, 157, P, MPAD, MP, nullptr, 40);
        reduce_softmax<<<2500, 256, 0, stream>>>(P, b2, out, 4);
    } else {
        // fully fused fallback (no split)
        gemm_k<64, 256, 2, 4, 1, 1><<<157, 512, 0, stream>>>(
            adj, N_ROWS, N_ROWS, N_ROWS, XWt, MP, 157, H, 256, MP, b1, 157);
        gemm_k<64, 64, 4, 2, 0, 0><<<157, 512, 0, stream>>>(
            H, 256, MP, 256, W2t, 256, 4, HWt, MP, MP, nullptr, 4);
        gemm_k<128, 64, 8, 1, 1, 2><<<79, 512, 0, stream>>>(
            adj, N_ROWS, N_ROWS, N_ROWS, HWt, MP, 157, out, 40, N_ROWS, b2, 157);
    }
}

// Round 9
// 226.738 us; speedup vs baseline: 1.9435x; 1.0998x over previous
//
#include <hip/hip_runtime.h>
#include <hip/hip_bf16.h>

typedef short s16x8 __attribute__((ext_vector_type(8)));
typedef short s16x4 __attribute__((ext_vector_type(4)));
typedef float f32x4 __attribute__((ext_vector_type(4)));
typedef unsigned u32x4 __attribute__((ext_vector_type(4)));
typedef unsigned u32x2 __attribute__((ext_vector_type(2)));

#define N_ROWS 10000
#define MP   10048   // padded adj dim (157*64)
#define MPAD 10112   // partial-buffer row stride (79*128, covers BM=128 grids)

#if defined(__has_builtin)
#if __has_builtin(__builtin_amdgcn_cvt_pk_fp8_f32)
#define HAS_CVT_FP8 1
#endif
#endif
#ifndef HAS_CVT_FP8
#define HAS_CVT_FP8 0
#endif

// native RNE f32->bf16
__device__ inline short f2bf(float f) {
    __hip_bfloat16 h = __float2bfloat16(f);
    return __builtin_bit_cast(short, h);
}
__device__ inline float bf2f(short b) {
    return __builtin_bit_cast(float, ((unsigned)(unsigned short)b) << 16);
}

// manual f32 -> e4m3 (RNE), valid for x in [0, 1.0]; flushes x < 2^-6 to 0
__device__ inline unsigned enc1(float x) {
    unsigned u = __builtin_bit_cast(unsigned, x);
    unsigned r = u + 0x7FFFFu + ((u >> 20) & 1u);   // RNE into 3-bit mantissa
    unsigned byte = (((r >> 23) - 120u) << 3) | ((r >> 20) & 7u);
    return (u < 0x3C800000u) ? 0u : byte;           // x < 2^-6 -> 0
}

// decode two e4m3 bytes (non-negative) -> packed bf16 pair; E=0 flushed to 0
__device__ inline unsigned dec2(unsigned b0, unsigned b1) {
    unsigned r0 = (b0 + 960u) << 4; r0 = (b0 < 8u) ? 0u : r0;
    unsigned r1 = (b1 + 960u) << 4; r1 = (b1 < 8u) ? 0u : r1;
    return r0 | (r1 << 16);
}

// swizzled LDS index (units: bf16 elements, rows of 64)
__device__ inline int swz(int row, int col) {
    return (row * 64 + col) ^ ((row & 7) << 3);
}

// ---------------------------------------------------------------------------
// Unified MFMA GEMM with depth-1 register prefetch.
//  C[M x BN] = A[M x K] * B[K x BN]
//  AMODE 0: A f32 row-major (converted to bf16 on the fly)
//  AMODE 1: A bf16 row-major
//  AMODE 2: A fp8-e4m3 row-major (BM==128 only), decoded to bf16 in staging
//  B: TRANSPOSED as Bt[BN][ldBt] bf16 (row n = column n of B)
//  CONV8 (AMODE 0 only): also emit the staged A tile as fp8 to Af8out[MP-ld]
//  K-split: blockIdx.y picks [y*ktPerSplit, min(+ktPerSplit, Ktiles))
//  EPI 0: store C^T bf16 -> Cp[gc*ldC + gm]
//  EPI 1: store relu(C + bias) bf16 row-major -> Cp[gm*ldC + gc]
//  EPI 2: logits = C + bias; row log_softmax; store f32, gc<40
//  EPI 3: store bf16 partial -> ((short*)Cp + y*ldC*BN)[gm*BN + gc]
// ---------------------------------------------------------------------------
template<int BM, int BN, int WM, int WN, int AMODE, int EPI, int CONV8>
__global__ __launch_bounds__(512)
void gemm_k(const void* __restrict__ Ap, int ldA, int Mval, int Kval,
            const short* __restrict__ Bt, int ldBt, int Ktiles,
            void* __restrict__ Cp, int ldC, int Cval,
            const float* __restrict__ bias, int ktPerSplit,
            unsigned char* __restrict__ Af8out)
{
    constexpr int WTM = BM / WM, WTN = BN / WN;
    constexpr int M_rep = WTM / 16, N_rep = WTN / 16;
    constexpr int AREP = (AMODE == 2) ? 1 : BM / 64, BREP = BN / 64;

    __shared__ alignas(16) short Alds[BM * 64];
    __shared__ alignas(16) short Blds[BN * 64];

    const int tid  = threadIdx.x;
    const int lane = tid & 63;
    const int w    = tid >> 6;
    const int wr   = w / WN, wc = w % WN;
    const int m0   = blockIdx.x * BM;

    float4 va0[AREP], va1[AREP];
    s16x8  vab[AREP];
    u32x4  v8;
    s16x8  vb[BREP];

    auto load_regs = [&](int kt) {
        const int k0 = kt * 64;
        if constexpr (AMODE == 2) {
            // BM==128: one 16-byte (16 elem) chunk per thread
            int row = tid >> 2, cc = (tid & 3) * 16;
            int gm  = m0 + row;
            u32x4 z = {0u, 0u, 0u, 0u};
            v8 = z;
            if (gm < Mval)
                v8 = *(const u32x4*)((const unsigned char*)Ap + (size_t)gm * ldA + k0 + cc);
        } else {
            #pragma unroll
            for (int rep = 0; rep < AREP; ++rep) {
                int e   = tid + rep * 512;
                int row = e >> 3, cc = (e & 7) * 8;
                int gm  = m0 + row, gk = k0 + cc;
                if constexpr (AMODE == 0) {
                    float4 z = {0.f, 0.f, 0.f, 0.f};
                    va0[rep] = z; va1[rep] = z;
                    if (gm < Mval && gk < Kval) {
                        const float* p = (const float*)Ap + (long)gm * ldA + gk;
                        va0[rep] = *(const float4*)p;
                        va1[rep] = *(const float4*)(p + 4);
                    }
                } else {
                    if (gm < Mval && gk < Kval) {
                        vab[rep] = *(const s16x8*)((const short*)Ap + (long)gm * ldA + gk);
                    } else {
                        s16x8 z;
                        #pragma unroll
                        for (int j = 0; j < 8; ++j) z[j] = 0;
                        vab[rep] = z;
                    }
                }
            }
        }
        #pragma unroll
        for (int rep = 0; rep < BREP; ++rep) {
            int e   = tid + rep * 512;
            int row = e >> 3, cc = (e & 7) * 8;
            vb[rep] = *(const s16x8*)(Bt + (long)row * ldBt + k0 + cc);
        }
    };

    auto write_lds = [&](int kt) {
        const int k0 = kt * 64;
        if constexpr (AMODE == 2) {
            int row = tid >> 2, cc = (tid & 3) * 16;
            unsigned vv[4] = {v8[0], v8[1], v8[2], v8[3]};
            unsigned q[8];
            #pragma unroll
            for (int i = 0; i < 4; ++i) {
                q[2*i]   = dec2(vv[i] & 0xffu, (vv[i] >> 8) & 0xffu);
                q[2*i+1] = dec2((vv[i] >> 16) & 0xffu, (vv[i] >> 24) & 0xffu);
            }
            u32x4 lo = {q[0], q[1], q[2], q[3]};
            u32x4 hi = {q[4], q[5], q[6], q[7]};
            *(u32x4*)(&Alds[swz(row, cc)])     = lo;
            *(u32x4*)(&Alds[swz(row, cc + 8)]) = hi;
        } else {
            #pragma unroll
            for (int rep = 0; rep < AREP; ++rep) {
                int e   = tid + rep * 512;
                int row = e >> 3, cc = (e & 7) * 8;
                s16x8 b;
                if constexpr (AMODE == 0) {
                    b[0]=f2bf(va0[rep].x); b[1]=f2bf(va0[rep].y);
                    b[2]=f2bf(va0[rep].z); b[3]=f2bf(va0[rep].w);
                    b[4]=f2bf(va1[rep].x); b[5]=f2bf(va1[rep].y);
                    b[6]=f2bf(va1[rep].z); b[7]=f2bf(va1[rep].w);
                } else {
                    b = vab[rep];
                }
                *(s16x8*)(&Alds[swz(row, cc)]) = b;
                if constexpr (CONV8) {
                    unsigned a8, b8;
#if HAS_CVT_FP8
                    a8 = (unsigned)__builtin_amdgcn_cvt_pk_fp8_f32(va0[rep].x, va0[rep].y, 0, false);
                    a8 = (unsigned)__builtin_amdgcn_cvt_pk_fp8_f32(va0[rep].z, va0[rep].w, (int)a8, true);
                    b8 = (unsigned)__builtin_amdgcn_cvt_pk_fp8_f32(va1[rep].x, va1[rep].y, 0, false);
                    b8 = (unsigned)__builtin_amdgcn_cvt_pk_fp8_f32(va1[rep].z, va1[rep].w, (int)b8, true);
#else
                    a8 = enc1(va0[rep].x) | (enc1(va0[rep].y) << 8)
                       | (enc1(va0[rep].z) << 16) | (enc1(va0[rep].w) << 24);
                    b8 = enc1(va1[rep].x) | (enc1(va1[rep].y) << 8)
                       | (enc1(va1[rep].z) << 16) | (enc1(va1[rep].w) << 24);
#endif
                    u32x2 st = {a8, b8};
                    *(u32x2*)(Af8out + (size_t)(m0 + row) * MP + (k0 + cc)) = st;
                }
            }
        }
        #pragma unroll
        for (int rep = 0; rep < BREP; ++rep) {
            int e   = tid + rep * 512;
            int row = e >> 3, cc = (e & 7) * 8;
            *(s16x8*)(&Blds[swz(row, cc)]) = vb[rep];
        }
    };

    f32x4 acc[M_rep][N_rep];
    const f32x4 zero4 = {0.f, 0.f, 0.f, 0.f};
    #pragma unroll
    for (int mi = 0; mi < M_rep; ++mi)
        #pragma unroll
        for (int nj = 0; nj < N_rep; ++nj) acc[mi][nj] = zero4;

    const int kt0 = blockIdx.y * ktPerSplit;
    int ktEnd = kt0 + ktPerSplit;
    if (ktEnd > Ktiles) ktEnd = Ktiles;

    load_regs(kt0);
    write_lds(kt0);

    for (int kt = kt0; kt < ktEnd; ++kt) {
        __syncthreads();
        if (kt + 1 < ktEnd) load_regs(kt + 1);
        #pragma unroll
        for (int kk = 0; kk < 2; ++kk) {
            const int krd = kk * 32 + (lane >> 4) * 8;
            s16x8 af[M_rep], bf[N_rep];
            #pragma unroll
            for (int mi = 0; mi < M_rep; ++mi) {
                int row = wr * WTM + mi * 16 + (lane & 15);
                af[mi] = *(const s16x8*)(&Alds[swz(row, krd)]);
            }
            #pragma unroll
            for (int nj = 0; nj < N_rep; ++nj) {
                int row = wc * WTN + nj * 16 + (lane & 15);
                bf[nj] = *(const s16x8*)(&Blds[swz(row, krd)]);
            }
            #pragma unroll
            for (int mi = 0; mi < M_rep; ++mi)
                #pragma unroll
                for (int nj = 0; nj < N_rep; ++nj)
                    acc[mi][nj] = __builtin_amdgcn_mfma_f32_16x16x32_bf16(
                        af[mi], bf[nj], acc[mi][nj], 0, 0, 0);
        }
        __syncthreads();
        if (kt + 1 < ktEnd) write_lds(kt + 1);
    }

    // ---- epilogue ----
    const int mbase = m0 + wr * WTM;
    if constexpr (EPI == 0) {
        short* CT = (short*)Cp;
        #pragma unroll
        for (int mi = 0; mi < M_rep; ++mi) {
            int gm = mbase + mi * 16 + (lane >> 4) * 4;
            if (gm >= Cval) continue;
            #pragma unroll
            for (int nj = 0; nj < N_rep; ++nj) {
                int gc = wc * WTN + nj * 16 + (lane & 15);
                s16x4 p;
                #pragma unroll
                for (int r = 0; r < 4; ++r) p[r] = f2bf(acc[mi][nj][r]);
                *(s16x4*)(CT + (long)gc * ldC + gm) = p;
            }
        }
    } else if constexpr (EPI == 1) {
        short* C = (short*)Cp;
        #pragma unroll
        for (int nj = 0; nj < N_rep; ++nj) {
            int gc = wc * WTN + nj * 16 + (lane & 15);
            float b = bias[gc];
            #pragma unroll
            for (int mi = 0; mi < M_rep; ++mi) {
                int gm = mbase + mi * 16 + (lane >> 4) * 4;
                #pragma unroll
                for (int r = 0; r < 4; ++r) {
                    float v = acc[mi][nj][r] + b;
                    v = fmaxf(v, 0.f);
                    C[(long)(gm + r) * ldC + gc] = f2bf(v);
                }
            }
        }
    } else if constexpr (EPI == 2) {
        float* out = (float*)Cp;
        const int gmb = mbase + (lane >> 4) * 4;
        #pragma unroll
        for (int r = 0; r < 4; ++r) {
            float v[4];
            float mx = -__builtin_inff();
            #pragma unroll
            for (int nj = 0; nj < 4; ++nj) {
                int gc = nj * 16 + (lane & 15);
                float vv = -__builtin_inff();
                if (gc < 40) vv = acc[0][nj][r] + bias[gc];
                v[nj] = vv;
                mx = fmaxf(mx, vv);
            }
            #pragma unroll
            for (int off = 1; off < 16; off <<= 1)
                mx = fmaxf(mx, __shfl_xor(mx, off));
            float s = 0.f;
            #pragma unroll
            for (int nj = 0; nj < 4; ++nj)
                s += (v[nj] == -__builtin_inff()) ? 0.f : __expf(v[nj] - mx);
            #pragma unroll
            for (int off = 1; off < 16; off <<= 1)
                s += __shfl_xor(s, off);
            float lse = mx + __logf(s);
            int gm = gmb + r;
            if (gm < Cval) {
                #pragma unroll
                for (int nj = 0; nj < 4; ++nj) {
                    int gc = nj * 16 + (lane & 15);
                    if (gc < 40) out[(long)gm * ldC + gc] = v[nj] - lse;
                }
            }
        }
    } else {
        // EPI == 3: bf16 partial store; ldC = partial row stride (MPAD)
        short* Cpart = (short*)Cp + (size_t)blockIdx.y * ldC * BN;
        #pragma unroll
        for (int nj = 0; nj < N_rep; ++nj) {
            int gc = wc * WTN + nj * 16 + (lane & 15);
            #pragma unroll
            for (int mi = 0; mi < M_rep; ++mi) {
                int gm = mbase + mi * 16 + (lane >> 4) * 4;
                #pragma unroll
                for (int r = 0; r < 4; ++r)
                    Cpart[(long)(gm + r) * BN + gc] = f2bf(acc[mi][nj][r]);
            }
        }
    }
}

// H = relu(sum_s P[s] + b1), bf16 [MP][256]; pad rows -> 0. P: bf16 partials.
__global__ __launch_bounds__(256)
void reduce_relu(const short* __restrict__ P, const float* __restrict__ b1,
                 short* __restrict__ H, int KS)
{
    int idx8 = blockIdx.x * 256 + threadIdx.x;
    int row  = idx8 >> 5;
    int col  = (idx8 & 31) * 8;
    s16x8 o;
    if (row < N_ROWS) {
        float s[8] = {0,0,0,0,0,0,0,0};
        if (KS == 8) {
            #pragma unroll
            for (int k = 0; k < 8; ++k) {
                s16x8 v = *(const s16x8*)(P + (size_t)k * MPAD * 256 + (size_t)row * 256 + col);
                #pragma unroll
                for (int j = 0; j < 8; ++j) s[j] += bf2f(v[j]);
            }
        } else {
            for (int k = 0; k < KS; ++k) {
                s16x8 v = *(const s16x8*)(P + (size_t)k * MPAD * 256 + (size_t)row * 256 + col);
                #pragma unroll
                for (int j = 0; j < 8; ++j) s[j] += bf2f(v[j]);
            }
        }
        #pragma unroll
        for (int j = 0; j < 8; ++j)
            o[j] = f2bf(fmaxf(s[j] + b1[col + j], 0.f));
    } else {
        #pragma unroll
        for (int j = 0; j < 8; ++j) o[j] = 0;
    }
    *(s16x8*)(H + (size_t)row * 256 + col) = o;
}

// out = log_softmax(sum_s P[s] + b2) over 40 cols; P rows 64 wide (bf16)
__global__ __launch_bounds__(256)
void reduce_softmax(const short* __restrict__ P, const float* __restrict__ b2,
                    float* __restrict__ out, int KS)
{
    int lane = threadIdx.x & 63;
    int row  = blockIdx.x * 4 + (threadIdx.x >> 6);
    if (row >= N_ROWS) return;
    float v = 0.f;
    if (KS == 16) {
        #pragma unroll
        for (int k = 0; k < 16; ++k)
            v += bf2f(P[(size_t)k * MPAD * 64 + (size_t)row * 64 + lane]);
    } else {
        for (int k = 0; k < KS; ++k)
            v += bf2f(P[(size_t)k * MPAD * 64 + (size_t)row * 64 + lane]);
    }
    float vv = (lane < 40) ? v + b2[lane] : -__builtin_inff();
    float mx = vv;
    #pragma unroll
    for (int off = 1; off < 64; off <<= 1)
        mx = fmaxf(mx, __shfl_xor(mx, off));
    float e = (lane < 40) ? __expf(vv - mx) : 0.f;
    float s = e;
    #pragma unroll
    for (int off = 1; off < 64; off <<= 1)
        s += __shfl_xor(s, off);
    float lse = mx + __logf(s);
    if (lane < 40) out[(size_t)row * 40 + lane] = vv - lse;
}

// merged weight prep
__global__ __launch_bounds__(256)
void prep_w(const float* __restrict__ W1, const float* __restrict__ W2,
            short* __restrict__ W1t, short* __restrict__ W2t)
{
    int bid = blockIdx.x, c = threadIdx.x;
    if (bid < 512) {
        W1t[c * 512 + bid] = f2bf(W1[bid * 256 + c]);
    } else {
        int k = bid - 512;
        if (c < 64) {
            float v = (c < 40) ? W2[k * 40 + c] : 0.f;
            W2t[c * 256 + k] = f2bf(v);
        }
    }
}

extern "C" void kernel_launch(void* const* d_in, const int* in_sizes, int n_in,
                              void* d_out, int out_size, void* d_ws, size_t ws_size,
                              hipStream_t stream)
{
    const float* feature = (const float*)d_in[0];  // [10000,512]
    const float* adj     = (const float*)d_in[1];  // [10000,10000]
    const float* W1      = (const float*)d_in[2];  // [512,256]
    const float* b1      = (const float*)d_in[3];  // [256]
    const float* W2      = (const float*)d_in[4];  // [256,40]
    const float* b2      = (const float*)d_in[5];  // [40]
    float* out = (float*)d_out;                    // [10000,40]

    char* w = (char*)d_ws;
    short* XWt = (short*)w;  w += 256L * MP * 2;      // [256][10048] bf16
    short* H   = (short*)w;  w += (long)MP * 256 * 2; // [10048][256] bf16
    short* HWt = (short*)w;  w += 64L * MP * 2;       // [64][10048] bf16
    short* W1t = (short*)w;  w += 256L * 512 * 2;     // [256][512] bf16
    short* W2t = (short*)w;  w += 64L * 256 * 2;      // [64][256] bf16
    char*  base_noF8 = w;                             // fallback P location
    unsigned char* adjF8 = (unsigned char*)w;  w += (size_t)MP * MP; // 101 MB fp8
    short* P   = (short*)w;                           // bf16 K-split partials
    size_t offFull = (size_t)((char*)P - (char*)d_ws);
    size_t offNo   = (size_t)(base_noF8 - (char*)d_ws);

    const size_t p2 = (size_t)MPAD * 256 * 2;   // one G2 partial buffer
    const size_t p4 = (size_t)MPAD * 64 * 2;    // one G4 partial buffer
    const size_t pmax = (8 * p2 > 16 * p4) ? 8 * p2 : 16 * p4;

    prep_w<<<768, 256, 0, stream>>>(W1, W2, W1t, W2t);

    // G1: XW = feature @ W1 -> XWt (transposed store)
    gemm_k<64, 256, 2, 4, 0, 0, 0><<<157, 512, 0, stream>>>(
        feature, 512, N_ROWS, 512, W1t, 512, 8, XWt, MP, MP, nullptr, 8, nullptr);

    if (ws_size >= offFull + pmax) {
        // full path: G2 emits fp8 adj image; G4 reads it (101 MB vs 400 MB)
        // G2: bf16 partials = adj @ XW, KS=8; + adjF8 emission
        gemm_k<64, 256, 2, 4, 0, 3, 1><<<dim3(157, 8), 512, 0, stream>>>(
            adj, N_ROWS, N_ROWS, N_ROWS, XWt, MP, 157, P, MPAD, MP, nullptr, 20, adjF8);
        // R1: H = relu(sum + b1)
        reduce_relu<<<MP / 8, 256, 0, stream>>>(P, b1, H, 8);
        // G3: HW = H @ W2 -> HWt
        gemm_k<64, 64, 4, 2, 1, 0, 0><<<157, 512, 0, stream>>>(
            H, 256, MP, 256, W2t, 256, 4, HWt, MP, MP, nullptr, 4, nullptr);
        // G4: bf16 partials = adjF8 @ HW, KS=16, BM=128 (fp8 A, decode in staging)
        gemm_k<128, 64, 4, 2, 2, 3, 0><<<dim3(79, 16), 512, 0, stream>>>(
            adjF8, MP, MP, MP, HWt, MP, 157, P, MPAD, MP, nullptr, 10, nullptr);
        // R2: out = log_softmax(sum + b2)
        reduce_softmax<<<2500, 256, 0, stream>>>(P, b2, out, 16);
    } else if (ws_size >= offNo + pmax) {
        // round-8 path (no fp8 image): G4 re-reads f32 adj
        short* P0 = (short*)base_noF8;
        gemm_k<64, 256, 2, 4, 0, 3, 0><<<dim3(157, 8), 512, 0, stream>>>(
            adj, N_ROWS, N_ROWS, N_ROWS, XWt, MP, 157, P0, MPAD, MP, nullptr, 20, nullptr);
        reduce_relu<<<MP / 8, 256, 0, stream>>>(P0, b1, H, 8);
        gemm_k<64, 64, 4, 2, 1, 0, 0><<<157, 512, 0, stream>>>(
            H, 256, MP, 256, W2t, 256, 4, HWt, MP, MP, nullptr, 4, nullptr);
        gemm_k<128, 64, 4, 2, 0, 3, 0><<<dim3(79, 16), 512, 0, stream>>>(
            adj, N_ROWS, N_ROWS, N_ROWS, HWt, MP, 157, P0, MPAD, MP, nullptr, 10, nullptr);
        reduce_softmax<<<2500, 256, 0, stream>>>(P0, b2, out, 16);
    } else if (ws_size >= offNo + 4 * p2) {
        // reduced split fallback (KS=4 both)
        short* P0 = (short*)base_noF8;
        gemm_k<64, 256, 2, 4, 0, 3, 0><<<dim3(157, 4), 512, 0, stream>>>(
            adj, N_ROWS, N_ROWS, N_ROWS, XWt, MP, 157, P0, MPAD, MP, nullptr, 40, nullptr);
        reduce_relu<<<MP / 8, 256, 0, stream>>>(P0, b1, H, 4);
        gemm_k<64, 64, 4, 2, 1, 0, 0><<<157, 512, 0, stream>>>(
            H, 256, MP, 256, W2t, 256, 4, HWt, MP, MP, nullptr, 4, nullptr);
        gemm_k<128, 64, 4, 2, 0, 3, 0><<<dim3(79, 4), 512, 0, stream>>>(
            adj, N_ROWS, N_ROWS, N_ROWS, HWt, MP, 157, P0, MPAD, MP, nullptr, 40, nullptr);
        reduce_softmax<<<2500, 256, 0, stream>>>(P0, b2, out, 4);
    } else {
        // fully fused fallback (no split)
        gemm_k<64, 256, 2, 4, 0, 1, 0><<<157, 512, 0, stream>>>(
            adj, N_ROWS, N_ROWS, N_ROWS, XWt, MP, 157, H, 256, MP, b1, 157, nullptr);
        gemm_k<64, 64, 4, 2, 1, 0, 0><<<157, 512, 0, stream>>>(
            H, 256, MP, 256, W2t, 256, 4, HWt, MP, MP, nullptr, 4, nullptr);
        gemm_k<128, 64, 8, 1, 0, 2, 0><<<79, 512, 0, stream>>>(
            adj, N_ROWS, N_ROWS, N_ROWS, HWt, MP, 157, out, 40, N_ROWS, b2, 157, nullptr);
    }
}